// Round 1
// 344.063 us; speedup vs baseline: 1.0149x; 1.0149x over previous
//
#include <hip/hip_runtime.h>

// ResFCEventuallyLayer — two-phase: (1) fp32->bf16 pre-convert into d_ws,
// (2) pure-bf16 m97-style MFMA GEMM (global_load_lds staging) + fused epilogue.
//   rs   = x @ W^T            (einsum "bj,ij->bi": both operands K-major)
//   out1 = relu(1 - beta + rs)
//   res  = relu(1 - (beta_res - (x + out1)));  LeakyReLU(res>=0) == identity
// fp32 in/out; bf16 MFMA compute (absmax 2.0 vs threshold 7.32 proven in R6).
//
// R7 single variable: staging via __builtin_amdgcn_global_load_lds width=16
// (direct HBM->LDS DMA, no VGPR round-trip). LDS layout unchanged — it was
// already contiguous in chunk order c = t, i.e. wave-uniform base + lane*16B,
// which is exactly the DMA's fixed scatter pattern (guide §5, m97/m104).

#define NDIM 4096

typedef __bf16 bf16x8 __attribute__((ext_vector_type(8)));
typedef float f32x4 __attribute__((ext_vector_type(4)));

__device__ unsigned short f2bf(float f) {
    unsigned int x;
    __builtin_memcpy(&x, &f, 4);
    unsigned int r = x + 0x7FFFu + ((x >> 16) & 1u);   // round-to-nearest-even
    return (unsigned short)(r >> 16);
}

__device__ unsigned int pack_bf2(float lo, float hi) {
    return (unsigned int)f2bf(lo) | ((unsigned int)f2bf(hi) << 16);
}

// Direct global->LDS DMA, 16 B per lane. LDS dest semantics: wave-uniform
// base + lane*16 (m104/m108) — pass the wave-uniform base pointer.
__device__ inline void gload16(const uint4* g, unsigned int* l) {
    __builtin_amdgcn_global_load_lds(
        (const __attribute__((address_space(1))) unsigned int*)g,
        (__attribute__((address_space(3))) unsigned int*)l,
        16, 0, 0);
}

// Phase 1: fp32 -> packed bf16. 8 elements per thread.
__global__ void convert_f32_bf16_kernel(const float* src, unsigned int* dst) {
    const size_t i = ((size_t)blockIdx.x * blockDim.x + threadIdx.x) * 8;
    float4 v0 = *(const float4*)(src + i);
    float4 v1 = *(const float4*)(src + i + 4);
    uint4 u;
    u.x = pack_bf2(v0.x, v0.y);
    u.y = pack_bf2(v0.z, v0.w);
    u.z = pack_bf2(v1.x, v1.y);
    u.w = pack_bf2(v1.z, v1.w);
    *(uint4*)(dst + i / 2) = u;
}

// Phase 2: bf16-staged GEMM, 128x128 tile, BK=32, 4 waves 2x2, 4x4 accs.
__global__ void ResFCEventuallyLayer_82205674045459_kernel(
    const unsigned int* Xbf, const unsigned int* Wbf,
    const float* X, const float* Bp, const float* Br,
    float* out)
{
    // Tiles: 128 rows x 32 k of bf16 = 8 KB each; row = 64 B = 4 uint4 chunks.
    __shared__ __align__(16) unsigned int sA[128 * 16];
    __shared__ __align__(16) unsigned int sB[128 * 16];

    const int t    = threadIdx.x;      // 0..255
    const int lane = t & 63;
    const int wave = t >> 6;           // 0..3
    const int quad = lane >> 4;        // 0..3
    const int l16  = lane & 15;
    const int wm   = wave >> 1;        // 0..1: 64-row half
    const int wn   = wave & 1;         // 0..1: 64-col half

    const int bm0 = blockIdx.y * 128;
    const int bn0 = blockIdx.x * 128;

    // Staging: 512 x 16B chunks per tile; thread t handles chunks t and t+256.
    // Chunk c: row = c>>2, 16B-slot-in-row = c&3; LDS byte offset = c*16.
    // Per wave w: chunks w*64+lane -> bytes w*1024 + lane*16  == DMA pattern.
    const int c0 = t, c1 = t + 256;
    const uint4* gA0 = (const uint4*)Xbf + (size_t)(bm0 + (c0 >> 2)) * 512 + (c0 & 3);
    const uint4* gA1 = (const uint4*)Xbf + (size_t)(bm0 + (c1 >> 2)) * 512 + (c1 & 3);
    const uint4* gB0 = (const uint4*)Wbf + (size_t)(bn0 + (c0 >> 2)) * 512 + (c0 & 3);
    const uint4* gB1 = (const uint4*)Wbf + (size_t)(bn0 + (c1 >> 2)) * 512 + (c1 & 3);

    // Wave-uniform LDS bases for the DMA (uint index; 1 uint4 chunk = 4 uints).
    unsigned int* lA0 = sA + wave * 256;          // bytes w*1024 .. +1023
    unsigned int* lA1 = sA + wave * 256 + 1024;   // second half (chunks t+256)
    unsigned int* lB0 = sB + wave * 256;
    unsigned int* lB1 = sB + wave * 256 + 1024;

    // Fragment pointers: lane holds A[m=l16][k=quad*8+j] -> 16 B at LDS row
    // (wm*64 + mt*16 + l16), byte offset quad*16. bf16x8 index = row*4 + quad.
    const bf16x8* pa = (const bf16x8*)sA + (wm * 64 + l16) * 4 + quad;
    const bf16x8* pb = (const bf16x8*)sB + (wn * 64 + l16) * 4 + quad;

    f32x4 acc[4][4];
    for (int i = 0; i < 4; i++)
        for (int j = 0; j < 4; j++)
            for (int r = 0; r < 4; r++)
                acc[i][j][r] = 0.0f;

    // 128 K-iterations; per iter the 32-k stripe = 4 uint4s per row.
    for (int s = 0; s < NDIM / 32; s++) {
        __syncthreads();               // prior iteration's frag reads complete
        gload16(gA0 + (size_t)s * 4, lA0);
        gload16(gA1 + (size_t)s * 4, lA1);
        gload16(gB0 + (size_t)s * 4, lB0);
        gload16(gB1 + (size_t)s * 4, lB1);
        __syncthreads();               // barrier drains vmcnt(0): tile visible

        bf16x8 af[4], bfr[4];
        for (int mt = 0; mt < 4; mt++) af[mt]  = pa[mt * 64];
        for (int nt = 0; nt < 4; nt++) bfr[nt] = pb[nt * 64];

        for (int mt = 0; mt < 4; mt++)
            for (int nt = 0; nt < 4; nt++)
                acc[mt][nt] = __builtin_amdgcn_mfma_f32_16x16x32_bf16(
                    af[mt], bfr[nt], acc[mt][nt], 0, 0, 0);
    }

    // Fused epilogue. C/D layout: n(col) = lane&15, m(row) = quad*4 + reg.
    const float one_m_beta = 1.0f - Bp[0];
    for (int nt = 0; nt < 4; nt++) {
        const int n = bn0 + wn * 64 + nt * 16 + l16;
        const float br = Br[n];
        for (int mt = 0; mt < 4; mt++) {
            const int mbase = bm0 + wm * 64 + mt * 16 + quad * 4;
            for (int r = 0; r < 4; r++) {
                const size_t idx = (size_t)(mbase + r) * NDIM + n;
                float v = acc[mt][nt][r] + one_m_beta;
                if (v < 0.0f) v = 0.0f;                 // relu(1 - beta + rowsum)
                float res = 1.0f - br + X[idx] + v;
                if (res < 0.0f) res = 0.0f;             // relu; leaky on relu == id
                out[idx] = res;
            }
        }
    }
}

// Fallback (R6 kernel, proven): in-loop conversion, no workspace needed.
__global__ void resfc_fallback_kernel(
    const float* X, const float* W,
    const float* Bp, const float* Br,
    float* out)
{
    __shared__ __align__(16) unsigned int sA[128 * 16];
    __shared__ __align__(16) unsigned int sB[128 * 16];

    const int t    = threadIdx.x;
    const int lane = t & 63;
    const int wave = t >> 6;
    const int quad = lane >> 4;
    const int l16  = lane & 15;
    const int wm   = wave >> 1;
    const int wn   = wave & 1;

    const int bm0 = blockIdx.y * 128;
    const int bn0 = blockIdx.x * 128;

    const float* gA[4];
    const float* gB[4];
    int ldsIdx[4];
    for (int c = 0; c < 4; c++) {
        const int ch   = t + c * 256;
        const int row  = ch >> 3;
        const int col4 = ch & 7;
        gA[c] = X + (size_t)(bm0 + row) * NDIM + col4 * 4;
        gB[c] = W + (size_t)(bn0 + row) * NDIM + col4 * 4;
        ldsIdx[c] = row * 16 + col4 * 2;
    }

    const bf16x8* pa = (const bf16x8*)sA + (wm * 64 + l16) * 4 + quad;
    const bf16x8* pb = (const bf16x8*)sB + (wn * 64 + l16) * 4 + quad;

    f32x4 acc[4][4];
    for (int i = 0; i < 4; i++)
        for (int j = 0; j < 4; j++)
            for (int r = 0; r < 4; r++)
                acc[i][j][r] = 0.0f;

    for (int k0 = 0; k0 < NDIM; k0 += 32) {
        float4 va[4], vb[4];
        for (int c = 0; c < 4; c++) {
            va[c] = *(const float4*)(gA[c] + k0);
            vb[c] = *(const float4*)(gB[c] + k0);
        }
        __syncthreads();
        for (int c = 0; c < 4; c++) {
            uint2 ua, ub;
            ua.x = pack_bf2(va[c].x, va[c].y);
            ua.y = pack_bf2(va[c].z, va[c].w);
            ub.x = pack_bf2(vb[c].x, vb[c].y);
            ub.y = pack_bf2(vb[c].z, vb[c].w);
            *(uint2*)(sA + ldsIdx[c]) = ua;
            *(uint2*)(sB + ldsIdx[c]) = ub;
        }
        __syncthreads();

        bf16x8 af[4], bfr[4];
        for (int mt = 0; mt < 4; mt++) af[mt]  = pa[mt * 64];
        for (int nt = 0; nt < 4; nt++) bfr[nt] = pb[nt * 64];

        for (int mt = 0; mt < 4; mt++)
            for (int nt = 0; nt < 4; nt++)
                acc[mt][nt] = __builtin_amdgcn_mfma_f32_16x16x32_bf16(
                    af[mt], bfr[nt], acc[mt][nt], 0, 0, 0);
    }

    const float one_m_beta = 1.0f - Bp[0];
    for (int nt = 0; nt < 4; nt++) {
        const int n = bn0 + wn * 64 + nt * 16 + l16;
        const float br = Br[n];
        for (int mt = 0; mt < 4; mt++) {
            const int mbase = bm0 + wm * 64 + mt * 16 + quad * 4;
            for (int r = 0; r < 4; r++) {
                const size_t idx = (size_t)(mbase + r) * NDIM + n;
                float v = acc[mt][nt][r] + one_m_beta;
                if (v < 0.0f) v = 0.0f;
                float res = 1.0f - br + X[idx] + v;
                if (res < 0.0f) res = 0.0f;
                out[idx] = res;
            }
        }
    }
}

extern "C" void kernel_launch(void* const* d_in, const int* in_sizes, int n_in,
                              void* d_out, int out_size, void* d_ws, size_t ws_size,
                              hipStream_t stream) {
    (void)in_sizes; (void)n_in; (void)out_size;

    const float* X  = (const float*)d_in[0];
    const float* W  = (const float*)d_in[1];
    const float* Bp = (const float*)d_in[2];
    const float* Br = (const float*)d_in[3];
    float* out      = (float*)d_out;

    const size_t elems   = (size_t)NDIM * NDIM;          // 16.7M per matrix
    const size_t bf_need = elems * 2 * 2;                // Xbf + Wbf, 2 B each

    dim3 gemm_grid(NDIM / 128, NDIM / 128);
    dim3 block(256);

    if (ws_size >= bf_need) {
        unsigned int* Xbf = (unsigned int*)d_ws;
        unsigned int* Wbf = (unsigned int*)d_ws + elems / 2;   // uint = 2 bf16

        dim3 cvt_grid((unsigned int)(elems / 8 / 256));
        hipLaunchKernelGGL(convert_f32_bf16_kernel, cvt_grid, block, 0, stream, X, Xbf);
        hipLaunchKernelGGL(convert_f32_bf16_kernel, cvt_grid, block, 0, stream, W, Wbf);
        hipLaunchKernelGGL(ResFCEventuallyLayer_82205674045459_kernel,
                           gemm_grid, block, 0, stream, Xbf, Wbf, X, Bp, Br, out);
    } else {
        hipLaunchKernelGGL(resfc_fallback_kernel,
                           gemm_grid, block, 0, stream, X, W, Bp, Br, out);
    }
}

// Round 3
// 322.988 us; speedup vs baseline: 1.0812x; 1.0652x over previous
//
#include <hip/hip_runtime.h>

// ResFCEventuallyLayer — (1) fp32->bf16 pre-convert into d_ws, (2) 256x256
// 8-phase deep-pipelined bf16 MFMA GEMM (m201 template, plain HIP) + fused
// epilogue.
//   rs   = x @ W^T            (einsum "bj,ij->bi": both operands K-major)
//   out1 = relu(1 - beta + rs)
//   res  = relu(1 - (beta_res - (x + out1)));  LeakyReLU(res>=0) == identity
//
// R9 fix (WAR race in R8): each wave reads BOTH k-sub columns of its A half
// across P1+P3, so A-halves' last read is P3 (not P1). A0 stage moved
// P2->P4 and P6->P8 (issue only after the 2nd barrier of the last-read
// phase). vmcnt cadence re-derived: 6 in flight + {2,0,2,4} issued = 14 at
// each VMCNT(6) -> drains exactly the previous tile's 8 loads. Invariant:
//   P4 drain: buf1(odd tile) complete before P5 reads it
//   P8 drain: buf0(even tile) complete before next P1 reads it
//
// Stage safety table (buf0 during P1..P4, staging tile 2j+2):
//   B-half0 last read P2 -> stage P3;  B-half1 last read P2 -> stage P4
//   A-half0 last read P3 -> stage P4;  A-half1 last read P3 -> stage P5
// (mirror for buf1 at P5..P8 staging tile 2j+3).

#define NDIM 4096

typedef __bf16 bf16x8 __attribute__((ext_vector_type(8)));
typedef float f32x4 __attribute__((ext_vector_type(4)));

__device__ unsigned short f2bf(float f) {
    unsigned int x;
    __builtin_memcpy(&x, &f, 4);
    unsigned int r = x + 0x7FFFu + ((x >> 16) & 1u);   // round-to-nearest-even
    return (unsigned short)(r >> 16);
}

__device__ unsigned int pack_bf2(float lo, float hi) {
    return (unsigned int)f2bf(lo) | ((unsigned int)f2bf(hi) << 16);
}

// Direct global->LDS DMA, 16 B per lane: wave-uniform LDS base + lane*16.
__device__ inline void gload16(const uint4* g, unsigned int* l) {
    __builtin_amdgcn_global_load_lds(
        (const __attribute__((address_space(1))) unsigned int*)g,
        (__attribute__((address_space(3))) unsigned int*)l,
        16, 0, 0);
}

// Phase 1: fp32 -> packed bf16. 8 elements per thread.
__global__ void convert_f32_bf16_kernel(const float* src, unsigned int* dst) {
    const size_t i = ((size_t)blockIdx.x * blockDim.x + threadIdx.x) * 8;
    float4 v0 = *(const float4*)(src + i);
    float4 v1 = *(const float4*)(src + i + 4);
    uint4 u;
    u.x = pack_bf2(v0.x, v0.y);
    u.y = pack_bf2(v0.z, v0.w);
    u.z = pack_bf2(v1.x, v1.y);
    u.w = pack_bf2(v1.z, v1.w);
    *(uint4*)(dst + i / 2) = u;
}

#define BAR()   __builtin_amdgcn_s_barrier()
#define LGKM0() do { asm volatile("s_waitcnt lgkmcnt(0)" ::: "memory"); \
                     __builtin_amdgcn_sched_barrier(0); } while (0)
#define VMCNT(n) asm volatile("s_waitcnt vmcnt(" #n ")" ::: "memory")
#define PRIO(x) __builtin_amdgcn_s_setprio(x)

// Stage one half-tile (2 rounds x 8KB). buf/h are literals.
#define STAGE_A(buf, h, S) do { \
    gload16(Ab4 + (offA[2*(h)]   + (S)*8), &sAU[buf][(2*(h))*2048   + wq]); \
    gload16(Ab4 + (offA[2*(h)+1] + (S)*8), &sAU[buf][(2*(h)+1)*2048 + wq]); \
} while (0)
#define STAGE_B(buf, h, S) do { \
    gload16(Bb4 + (offB[2*(h)]   + (S)*8), &sBU[buf][(2*(h))*2048   + wq]); \
    gload16(Bb4 + (offB[2*(h)+1] + (S)*8), &sBU[buf][(2*(h)+1)*2048 + wq]); \
} while (0)

// ds-read a 4-mt A half (8 x ds_read_b128) / 2-nt B half (4 x ds_read_b128).
#define READ_A4(dst, pbuf, mt0) do { \
    _Pragma("unroll") for (int _m = 0; _m < 4; _m++) { \
        dst[_m][0] = (pbuf)[afB + ((mt0) + _m) * 128]; \
        dst[_m][1] = (pbuf)[afB + ((mt0) + _m) * 128 + 64]; } \
} while (0)
#define READ_B2(dst, pbuf, nt0) do { \
    _Pragma("unroll") for (int _n = 0; _n < 2; _n++) { \
        dst[_n][0] = (pbuf)[bfB + ((nt0) + _n) * 128]; \
        dst[_n][1] = (pbuf)[bfB + ((nt0) + _n) * 128 + 64]; } \
} while (0)

// One C-quadrant x K=64: 4mt x 2nt x 2ksub = 16 MFMA.
#define MM16(afr, bfr, mt0, nt0) do { \
    _Pragma("unroll") for (int _m = 0; _m < 4; _m++) \
    _Pragma("unroll") for (int _n = 0; _n < 2; _n++) { \
        acc[(mt0)+_m][(nt0)+_n] = __builtin_amdgcn_mfma_f32_16x16x32_bf16( \
            afr[_m][0], bfr[_n][0], acc[(mt0)+_m][(nt0)+_n], 0, 0, 0); \
        acc[(mt0)+_m][(nt0)+_n] = __builtin_amdgcn_mfma_f32_16x16x32_bf16( \
            afr[_m][1], bfr[_n][1], acc[(mt0)+_m][(nt0)+_n], 0, 0, 0); } \
} while (0)

// Phase 2: 256x256 tile, BK=64, 8 waves (2Mx4N), 8-phase counted-vmcnt loop.
__global__ void __launch_bounds__(512, 2)
ResFCEventuallyLayer_82205674045459_kernel(
    const unsigned int* Xbf, const unsigned int* Wbf,
    const float* X, const float* Bp, const float* Br,
    float* out)
{
    // Per buffer: 256 rows x 64 k x bf16 = 32KB = 32 subtiles x 1KB.
    // Subtile (sr = row>>4, sc = kcol>>5) at byte (sr*2+sc)*1024; within:
    // r = row&15, phys chunk-in-row = logical chunk ^ ((r>>3)<<1).
    __shared__ __align__(16) unsigned int sAU[2][8192];
    __shared__ __align__(16) unsigned int sBU[2][8192];

    const int t    = threadIdx.x;      // 0..511
    const int lane = t & 63;
    const int wave = t >> 6;           // 0..7
    const int quad = lane >> 4;        // 0..3
    const int l16  = lane & 15;
    const int wm   = wave >> 2;        // 0..1: 128-row half
    const int wn   = wave & 3;         // 0..3: 64-col quarter
    const int wq   = wave * 256;       // LDS uint offset of this wave's 1KB DMA slice

    // 256 blocks total (= 1/CU); bijective XCD swizzle (256 % 8 == 0).
    const int bid = blockIdx.x;
    const int swz = ((bid & 7) << 5) | (bid >> 3);
    const int bm0 = (swz >> 4) * 256;
    const int bn0 = (swz & 15) * 256;

    const uint4* Ab4 = (const uint4*)Xbf;   // 512 uint4 per global row
    const uint4* Bb4 = (const uint4*)Wbf;

    // Staging inverse-swizzle: DMA round rr writes phys chunks p = rr*512 + t
    // (lane*16B within wave slice). Invert phys->logical for the global src.
    int offA[4], offB[4];
#pragma unroll
    for (int rr = 0; rr < 4; rr++) {
        const int p   = rr * 512 + t;
        const int r   = (p >> 2) & 15;
        const int sub = p >> 6;               // 0..31
        const int sr  = sub >> 1, sc = sub & 1;
        const int c8  = (p & 3) ^ (((r >> 3) & 1) << 1);
        const int row = sr * 16 + r;
        const int gc  = sc * 4 + c8;          // logical 8-col chunk in K-tile
        offA[rr] = (bm0 + row) * 512 + gc;
        offB[rr] = (bn0 + row) * 512 + gc;
    }

    // Fragment ds_read addressing (matches the staged swizzle):
    // byte = subtile*1024 + l16*64 + (quad*16 ^ ((l16>>3)<<5)); conflict-free.
    const int laneByte = l16 * 64 + ((quad * 16) ^ (((l16 >> 3) & 1) << 5));
    const int afB = (wm * 16384 + laneByte) >> 4;   // bf16x8 units
    const int bfB = (wn * 8192  + laneByte) >> 4;

    const bf16x8* pA0 = (const bf16x8*)sAU[0];
    const bf16x8* pA1 = (const bf16x8*)sAU[1];
    const bf16x8* pB0 = (const bf16x8*)sBU[0];
    const bf16x8* pB1 = (const bf16x8*)sBU[1];

    f32x4 acc[8][4];
#pragma unroll
    for (int i = 0; i < 8; i++)
#pragma unroll
        for (int j = 0; j < 4; j++)
#pragma unroll
            for (int r = 0; r < 4; r++)
                acc[i][j][r] = 0.0f;

    bf16x8 af0[4][2], af1[4][2], bf0[2][2], bf1[2][2];

    // Prologue: tile0 (A0,B0,B1,A1) + tile1 (A0,B0,B1) = 7 halves, 14 loads.
    STAGE_A(0, 0, 0); STAGE_B(0, 0, 0); STAGE_B(0, 1, 0); STAGE_A(0, 1, 0);
    STAGE_A(1, 0, 1); STAGE_B(1, 0, 1); STAGE_B(1, 1, 1);
    VMCNT(6);          // tile0's 8 loads landed; tile1's 6 in flight
    BAR();

    // 64 K-tiles, 2 per iteration (buf0 = even tile, buf1 = odd tile).
    for (int j = 0; j < 32; j++) {
        const int S1 = 2 * j + 1;              // <= 63, no clamp
        const int S2 = (2 * j + 2) & 63;       // garbage-safe wrap on last iter
        const int S3 = (2 * j + 3) & 63;

        // ---- tile 2j (buf0) ----
        // P1
        READ_A4(af0, pA0, 0); READ_B2(bf0, pB0, 0);      // 12 ds_read_b128
        STAGE_A(1, 1, S1);                               // tile 2j+1 A1 (buf1 A1 last read prev P7)
        BAR(); LGKM0();
        PRIO(1); MM16(af0, bf0, 0, 0); PRIO(0);          // Q00
        BAR();
        // P2 (no stage: every buf0 half still has pending reads)
        READ_B2(bf1, pB0, 2);                            // 4 reads
        BAR(); LGKM0();
        PRIO(1); MM16(af0, bf1, 0, 2); PRIO(0);          // Q01
        BAR();
        // P3
        READ_A4(af1, pA0, 4);                            // 8 reads
        STAGE_B(0, 0, S2);                               // tile 2j+2 B0 (last read P2)
        BAR(); LGKM0();
        PRIO(1); MM16(af1, bf1, 4, 2); PRIO(0);          // Q11
        BAR();
        // P4 (no reads; bf0 still live from P1)
        STAGE_B(0, 1, S2);                               // tile 2j+2 B1 (last read P2)
        STAGE_A(0, 0, S2);                               // tile 2j+2 A0 (last read P3)
        BAR();
        PRIO(1); MM16(af1, bf0, 4, 0); PRIO(0);          // Q10
        VMCNT(6);      // drains tile1's 6 + A1(2j+1): buf1 complete for P5
        BAR();

        // ---- tile 2j+1 (buf1) ----
        // P5
        READ_A4(af0, pA1, 0); READ_B2(bf0, pB1, 0);
        STAGE_A(0, 1, S2);                               // tile 2j+2 A1 (last read P3)
        BAR(); LGKM0();
        PRIO(1); MM16(af0, bf0, 0, 0); PRIO(0);
        BAR();
        // P6 (no stage: every buf1 half still has pending reads)
        READ_B2(bf1, pB1, 2);
        BAR(); LGKM0();
        PRIO(1); MM16(af0, bf1, 0, 2); PRIO(0);
        BAR();
        // P7
        READ_A4(af1, pA1, 4);
        STAGE_B(1, 0, S3);                               // tile 2j+3 B0 (last read P6)
        BAR(); LGKM0();
        PRIO(1); MM16(af1, bf1, 4, 2); PRIO(0);
        BAR();
        // P8
        STAGE_B(1, 1, S3);                               // tile 2j+3 B1 (last read P6)
        STAGE_A(1, 0, S3);                               // tile 2j+3 A0 (last read P7)
        BAR();
        PRIO(1); MM16(af1, bf0, 4, 0); PRIO(0);
        VMCNT(6);      // drains tile(2j+2)'s B0,B1,A0,A1: buf0 complete for next P1
        BAR();
    }

    // Fused epilogue. C/D layout: n(col) = lane&15, m(row) = quad*4 + reg.
    const float one_m_beta = 1.0f - Bp[0];
#pragma unroll
    for (int nt = 0; nt < 4; nt++) {
        const int n = bn0 + wn * 64 + nt * 16 + l16;
        const float br = Br[n];
#pragma unroll
        for (int mt = 0; mt < 8; mt++) {
            const int mbase = bm0 + wm * 128 + mt * 16 + quad * 4;
#pragma unroll
            for (int r = 0; r < 4; r++) {
                const size_t idx = (size_t)(mbase + r) * NDIM + n;
                float v = acc[mt][nt][r] + one_m_beta;
                if (v < 0.0f) v = 0.0f;                 // relu(1 - beta + rowsum)
                float res = 1.0f - br + X[idx] + v;
                if (res < 0.0f) res = 0.0f;             // relu; leaky on relu == id
                out[idx] = res;
            }
        }
    }
}

// Fallback (R6 kernel, proven): in-loop conversion, no workspace needed.
__global__ void resfc_fallback_kernel(
    const float* X, const float* W,
    const float* Bp, const float* Br,
    float* out)
{
    __shared__ __align__(16) unsigned int sA[128 * 16];
    __shared__ __align__(16) unsigned int sB[128 * 16];

    const int t    = threadIdx.x;
    const int lane = t & 63;
    const int wave = t >> 6;
    const int quad = lane >> 4;
    const int l16  = lane & 15;
    const int wm   = wave >> 1;
    const int wn   = wave & 1;

    const int bm0 = blockIdx.y * 128;
    const int bn0 = blockIdx.x * 128;

    const float* gA[4];
    const float* gB[4];
    int ldsIdx[4];
    for (int c = 0; c < 4; c++) {
        const int ch   = t + c * 256;
        const int row  = ch >> 3;
        const int col4 = ch & 7;
        gA[c] = X + (size_t)(bm0 + row) * NDIM + col4 * 4;
        gB[c] = W + (size_t)(bn0 + row) * NDIM + col4 * 4;
        ldsIdx[c] = row * 16 + col4 * 2;
    }

    const bf16x8* pa = (const bf16x8*)sA + (wm * 64 + l16) * 4 + quad;
    const bf16x8* pb = (const bf16x8*)sB + (wn * 64 + l16) * 4 + quad;

    f32x4 acc[4][4];
    for (int i = 0; i < 4; i++)
        for (int j = 0; j < 4; j++)
            for (int r = 0; r < 4; r++)
                acc[i][j][r] = 0.0f;

    for (int k0 = 0; k0 < NDIM; k0 += 32) {
        float4 va[4], vb[4];
        for (int c = 0; c < 4; c++) {
            va[c] = *(const float4*)(gA[c] + k0);
            vb[c] = *(const float4*)(gB[c] + k0);
        }
        __syncthreads();
        for (int c = 0; c < 4; c++) {
            uint2 ua, ub;
            ua.x = pack_bf2(va[c].x, va[c].y);
            ua.y = pack_bf2(va[c].z, va[c].w);
            ub.x = pack_bf2(vb[c].x, vb[c].y);
            ub.y = pack_bf2(vb[c].z, vb[c].w);
            *(uint2*)(sA + ldsIdx[c]) = ua;
            *(uint2*)(sB + ldsIdx[c]) = ub;
        }
        __syncthreads();

        bf16x8 af[4], bfr[4];
        for (int mt = 0; mt < 4; mt++) af[mt]  = pa[mt * 64];
        for (int nt = 0; nt < 4; nt++) bfr[nt] = pb[nt * 64];

        for (int mt = 0; mt < 4; mt++)
            for (int nt = 0; nt < 4; nt++)
                acc[mt][nt] = __builtin_amdgcn_mfma_f32_16x16x32_bf16(
                    af[mt], bfr[nt], acc[mt][nt], 0, 0, 0);
    }

    const float one_m_beta = 1.0f - Bp[0];
    for (int nt = 0; nt < 4; nt++) {
        const int n = bn0 + wn * 64 + nt * 16 + l16;
        const float br = Br[n];
        for (int mt = 0; mt < 4; mt++) {
            const int mbase = bm0 + wm * 64 + mt * 16 + quad * 4;
            for (int r = 0; r < 4; r++) {
                const size_t idx = (size_t)(mbase + r) * NDIM + n;
                float v = acc[mt][nt][r] + one_m_beta;
                if (v < 0.0f) v = 0.0f;
                float res = 1.0f - br + X[idx] + v;
                if (res < 0.0f) res = 0.0f;
                out[idx] = res;
            }
        }
    }
}

extern "C" void kernel_launch(void* const* d_in, const int* in_sizes, int n_in,
                              void* d_out, int out_size, void* d_ws, size_t ws_size,
                              hipStream_t stream) {
    (void)in_sizes; (void)n_in; (void)out_size;

    const float* X  = (const float*)d_in[0];
    const float* W  = (const float*)d_in[1];
    const float* Bp = (const float*)d_in[2];
    const float* Br = (const float*)d_in[3];
    float* out      = (float*)d_out;

    const size_t elems   = (size_t)NDIM * NDIM;          // 16.7M per matrix
    const size_t bf_need = elems * 2 * 2;                // Xbf + Wbf, 2 B each

    dim3 block(256);

    if (ws_size >= bf_need) {
        unsigned int* Xbf = (unsigned int*)d_ws;
        unsigned int* Wbf = (unsigned int*)d_ws + elems / 2;   // uint = 2 bf16

        dim3 cvt_grid((unsigned int)(elems / 8 / 256));
        hipLaunchKernelGGL(convert_f32_bf16_kernel, cvt_grid, block, 0, stream, X, Xbf);
        hipLaunchKernelGGL(convert_f32_bf16_kernel, cvt_grid, block, 0, stream, W, Wbf);
        hipLaunchKernelGGL(ResFCEventuallyLayer_82205674045459_kernel,
                           dim3(256), dim3(512), 0, stream, Xbf, Wbf, X, Bp, Br, out);
    } else {
        hipLaunchKernelGGL(resfc_fallback_kernel,
                           dim3(NDIM / 128, NDIM / 128), block, 0, stream,
                           X, W, Bp, Br, out);
    }
}

// Round 4
// 318.457 us; speedup vs baseline: 1.0966x; 1.0142x over previous
//
#include <hip/hip_runtime.h>

// ResFCEventuallyLayer — (1) fp32->bf16 pre-convert into d_ws, (2) 256x256
// 8-phase deep-pipelined bf16 MFMA GEMM + fused epilogue.
//   rs   = x @ W^T            (einsum "bj,ij->bi": both operands K-major)
//   out1 = relu(1 - beta + rs)
//   res  = relu(1 - (beta_res - (x + out1)));  LeakyReLU(res>=0) == identity
//
// R10 change (vs R9, which passed at 171us GEMM / MfmaUtil 33%): relax the
// per-phase serialization. R9 had [reads] BAR lgkmcnt(0)+sched_barrier(0)
// [16 MFMA] BAR per phase -> LDS drain never overlaps MFMA (half of m201's
// efficiency, exactly). Now: ONE barrier per phase; no manual lgkm drain
// (ds_reads are compiler-visible loads -> fine-grained lgkmcnt(4/3/1/0),
// m97-style); MM16 reordered ksub-outer (8 independent MFMAs between
// dependent acc pairs, bit-identical per-acc order).
//
// Fence audit (minimal set kept):
//  - WAR (stage overwriting half H): one BAR after H's last-read phase.
//    Wave's barrier arrival implies its reads done (every read is consumed
//    by a same-phase MFMA whose lgkm wait precedes arrival).
//  - RAW (reading refilled buffer): VMCNT(6) [asm w/ "memory" clobber, also
//    a compiler fence] + BAR at P4/P8. In-flight invariant unchanged:
//    6 + {2,0,2,4} issued = 14 at each VMCNT(6) -> drains prev tile's 8.
//  Stage placement (tile 2j+2 while computing buf0): B0@P3 (B last read
//  P2), B1+A0@P4, A1@P5 (A last read P3); mirror for buf1.

#define NDIM 4096

typedef __bf16 bf16x8 __attribute__((ext_vector_type(8)));
typedef float f32x4 __attribute__((ext_vector_type(4)));

__device__ unsigned short f2bf(float f) {
    unsigned int x;
    __builtin_memcpy(&x, &f, 4);
    unsigned int r = x + 0x7FFFu + ((x >> 16) & 1u);   // round-to-nearest-even
    return (unsigned short)(r >> 16);
}

__device__ unsigned int pack_bf2(float lo, float hi) {
    return (unsigned int)f2bf(lo) | ((unsigned int)f2bf(hi) << 16);
}

// Direct global->LDS DMA, 16 B per lane: wave-uniform LDS base + lane*16.
__device__ inline void gload16(const uint4* g, unsigned int* l) {
    __builtin_amdgcn_global_load_lds(
        (const __attribute__((address_space(1))) unsigned int*)g,
        (__attribute__((address_space(3))) unsigned int*)l,
        16, 0, 0);
}

// Phase 1: fp32 -> packed bf16. 8 elements per thread.
__global__ void convert_f32_bf16_kernel(const float* src, unsigned int* dst) {
    const size_t i = ((size_t)blockIdx.x * blockDim.x + threadIdx.x) * 8;
    float4 v0 = *(const float4*)(src + i);
    float4 v1 = *(const float4*)(src + i + 4);
    uint4 u;
    u.x = pack_bf2(v0.x, v0.y);
    u.y = pack_bf2(v0.z, v0.w);
    u.z = pack_bf2(v1.x, v1.y);
    u.w = pack_bf2(v1.z, v1.w);
    *(uint4*)(dst + i / 2) = u;
}

#define BAR()   __builtin_amdgcn_s_barrier()
#define VMCNT(n) asm volatile("s_waitcnt vmcnt(" #n ")" ::: "memory")
#define PRIO(x) __builtin_amdgcn_s_setprio(x)

// Stage one half-tile (2 rounds x 8KB). buf/h are literals.
#define STAGE_A(buf, h, S) do { \
    gload16(Ab4 + (offA[2*(h)]   + (S)*8), &sAU[buf][(2*(h))*2048   + wq]); \
    gload16(Ab4 + (offA[2*(h)+1] + (S)*8), &sAU[buf][(2*(h)+1)*2048 + wq]); \
} while (0)
#define STAGE_B(buf, h, S) do { \
    gload16(Bb4 + (offB[2*(h)]   + (S)*8), &sBU[buf][(2*(h))*2048   + wq]); \
    gload16(Bb4 + (offB[2*(h)+1] + (S)*8), &sBU[buf][(2*(h)+1)*2048 + wq]); \
} while (0)

// ds-read a 4-mt A half (8 x ds_read_b128) / 2-nt B half (4 x ds_read_b128).
#define READ_A4(dst, pbuf, mt0) do { \
    _Pragma("unroll") for (int _m = 0; _m < 4; _m++) { \
        dst[_m][0] = (pbuf)[afB + ((mt0) + _m) * 128]; \
        dst[_m][1] = (pbuf)[afB + ((mt0) + _m) * 128 + 64]; } \
} while (0)
#define READ_B2(dst, pbuf, nt0) do { \
    _Pragma("unroll") for (int _n = 0; _n < 2; _n++) { \
        dst[_n][0] = (pbuf)[bfB + ((nt0) + _n) * 128]; \
        dst[_n][1] = (pbuf)[bfB + ((nt0) + _n) * 128 + 64]; } \
} while (0)

// One C-quadrant x K=64: ksub OUTER so the 8 MFMAs inside each ksub pass are
// mutually independent (dependent acc pairs separated by 8 issues).
// Per-acc order unchanged (k0 then k1): bit-identical to R9.
#define MM16(afr, bfr, mt0, nt0) do { \
    _Pragma("unroll") for (int _k = 0; _k < 2; _k++) \
    _Pragma("unroll") for (int _m = 0; _m < 4; _m++) \
    _Pragma("unroll") for (int _n = 0; _n < 2; _n++) \
        acc[(mt0)+_m][(nt0)+_n] = __builtin_amdgcn_mfma_f32_16x16x32_bf16( \
            afr[_m][_k], bfr[_n][_k], acc[(mt0)+_m][(nt0)+_n], 0, 0, 0); \
} while (0)

// Phase 2: 256x256 tile, BK=64, 8 waves (2Mx4N), 8-phase counted-vmcnt loop.
__global__ void __launch_bounds__(512, 2)
ResFCEventuallyLayer_82205674045459_kernel(
    const unsigned int* Xbf, const unsigned int* Wbf,
    const float* X, const float* Bp, const float* Br,
    float* out)
{
    // Per buffer: 256 rows x 64 k x bf16 = 32KB = 32 subtiles x 1KB.
    // Subtile (sr = row>>4, sc = kcol>>5) at byte (sr*2+sc)*1024; within:
    // r = row&15, phys chunk-in-row = logical chunk ^ ((r>>3)<<1).
    __shared__ __align__(16) unsigned int sAU[2][8192];
    __shared__ __align__(16) unsigned int sBU[2][8192];

    const int t    = threadIdx.x;      // 0..511
    const int lane = t & 63;
    const int wave = t >> 6;           // 0..7
    const int quad = lane >> 4;        // 0..3
    const int l16  = lane & 15;
    const int wm   = wave >> 2;        // 0..1: 128-row half
    const int wn   = wave & 3;         // 0..3: 64-col quarter
    const int wq   = wave * 256;       // LDS uint offset of this wave's 1KB DMA slice

    // 256 blocks total (= 1/CU); bijective XCD swizzle (256 % 8 == 0).
    const int bid = blockIdx.x;
    const int swz = ((bid & 7) << 5) | (bid >> 3);
    const int bm0 = (swz >> 4) * 256;
    const int bn0 = (swz & 15) * 256;

    const uint4* Ab4 = (const uint4*)Xbf;   // 512 uint4 per global row
    const uint4* Bb4 = (const uint4*)Wbf;

    // Staging inverse-swizzle: DMA round rr writes phys chunks p = rr*512 + t
    // (lane*16B within wave slice). Invert phys->logical for the global src.
    int offA[4], offB[4];
#pragma unroll
    for (int rr = 0; rr < 4; rr++) {
        const int p   = rr * 512 + t;
        const int r   = (p >> 2) & 15;
        const int sub = p >> 6;               // 0..31
        const int sr  = sub >> 1, sc = sub & 1;
        const int c8  = (p & 3) ^ (((r >> 3) & 1) << 1);
        const int row = sr * 16 + r;
        const int gc  = sc * 4 + c8;          // logical 8-col chunk in K-tile
        offA[rr] = (bm0 + row) * 512 + gc;
        offB[rr] = (bn0 + row) * 512 + gc;
    }

    // Fragment ds_read addressing (matches the staged swizzle):
    // byte = subtile*1024 + l16*64 + (quad*16 ^ ((l16>>3)<<5)); conflict-free.
    const int laneByte = l16 * 64 + ((quad * 16) ^ (((l16 >> 3) & 1) << 5));
    const int afB = (wm * 16384 + laneByte) >> 4;   // bf16x8 units
    const int bfB = (wn * 8192  + laneByte) >> 4;

    const bf16x8* pA0 = (const bf16x8*)sAU[0];
    const bf16x8* pA1 = (const bf16x8*)sAU[1];
    const bf16x8* pB0 = (const bf16x8*)sBU[0];
    const bf16x8* pB1 = (const bf16x8*)sBU[1];

    f32x4 acc[8][4];
#pragma unroll
    for (int i = 0; i < 8; i++)
#pragma unroll
        for (int j = 0; j < 4; j++)
#pragma unroll
            for (int r = 0; r < 4; r++)
                acc[i][j][r] = 0.0f;

    bf16x8 af0[4][2], af1[4][2], bf0[2][2], bf1[2][2];

    // Prologue: tile0 (A0,B0,B1,A1) + tile1 (A0,B0,B1) = 7 halves, 14 loads.
    STAGE_A(0, 0, 0); STAGE_B(0, 0, 0); STAGE_B(0, 1, 0); STAGE_A(0, 1, 0);
    STAGE_A(1, 0, 1); STAGE_B(1, 0, 1); STAGE_B(1, 1, 1);
    VMCNT(6);          // tile0's 8 loads landed; tile1's 6 in flight
    BAR();

    // 64 K-tiles, 2 per iteration (buf0 = even tile, buf1 = odd tile).
    // One barrier per phase (at end); stages issued at phase top.
    for (int j = 0; j < 32; j++) {
        const int S1 = 2 * j + 1;              // <= 63, no clamp
        const int S2 = (2 * j + 2) & 63;       // garbage-safe wrap on last iter
        const int S3 = (2 * j + 3) & 63;

        // ---- tile 2j (buf0) ----
        // P1: stage buf1.A1 (last read prev P7, fenced by P7's BAR)
        STAGE_A(1, 1, S1);
        READ_A4(af0, pA0, 0); READ_B2(bf0, pB0, 0);
        PRIO(1); MM16(af0, bf0, 0, 0); PRIO(0);          // Q00
        BAR();
        // P2: no stage (all buf0 halves still have pending reads)
        READ_B2(bf1, pB0, 2);
        PRIO(1); MM16(af0, bf1, 0, 2); PRIO(0);          // Q01
        BAR();
        // P3: stage buf0.B0 for tile 2j+2 (B last read P2, fenced P2 BAR)
        STAGE_B(0, 0, S2);
        READ_A4(af1, pA0, 4);
        PRIO(1); MM16(af1, bf1, 4, 2); PRIO(0);          // Q11
        BAR();
        // P4: stage buf0.B1 + buf0.A0 (A last read P3, fenced P3 BAR)
        STAGE_B(0, 1, S2);
        STAGE_A(0, 0, S2);
        PRIO(1); MM16(af1, bf0, 4, 0); PRIO(0);          // Q10
        VMCNT(6);      // drains tile(2j+1)'s 8 loads: buf1 complete for P5
        BAR();

        // ---- tile 2j+1 (buf1) ----
        // P5: stage buf0.A1 (last read P3)
        STAGE_A(0, 1, S2);
        READ_A4(af0, pA1, 0); READ_B2(bf0, pB1, 0);
        PRIO(1); MM16(af0, bf0, 0, 0); PRIO(0);
        BAR();
        // P6
        READ_B2(bf1, pB1, 2);
        PRIO(1); MM16(af0, bf1, 0, 2); PRIO(0);
        BAR();
        // P7: stage buf1.B0 for tile 2j+3 (last read P6)
        STAGE_B(1, 0, S3);
        READ_A4(af1, pA1, 4);
        PRIO(1); MM16(af1, bf1, 4, 2); PRIO(0);
        BAR();
        // P8: stage buf1.B1 + buf1.A0 (last read P7)
        STAGE_B(1, 1, S3);
        STAGE_A(1, 0, S3);
        PRIO(1); MM16(af1, bf0, 4, 0); PRIO(0);
        VMCNT(6);      // drains tile(2j+2)'s 8 loads: buf0 complete for next P1
        BAR();
    }

    // Fused epilogue. C/D layout: n(col) = lane&15, m(row) = quad*4 + reg.
    const float one_m_beta = 1.0f - Bp[0];
#pragma unroll
    for (int nt = 0; nt < 4; nt++) {
        const int n = bn0 + wn * 64 + nt * 16 + l16;
        const float br = Br[n];
#pragma unroll
        for (int mt = 0; mt < 8; mt++) {
            const int mbase = bm0 + wm * 128 + mt * 16 + quad * 4;
#pragma unroll
            for (int r = 0; r < 4; r++) {
                const size_t idx = (size_t)(mbase + r) * NDIM + n;
                float v = acc[mt][nt][r] + one_m_beta;
                if (v < 0.0f) v = 0.0f;                 // relu(1 - beta + rowsum)
                float res = 1.0f - br + X[idx] + v;
                if (res < 0.0f) res = 0.0f;             // relu; leaky on relu == id
                out[idx] = res;
            }
        }
    }
}

// Fallback (R6 kernel, proven): in-loop conversion, no workspace needed.
__global__ void resfc_fallback_kernel(
    const float* X, const float* W,
    const float* Bp, const float* Br,
    float* out)
{
    __shared__ __align__(16) unsigned int sA[128 * 16];
    __shared__ __align__(16) unsigned int sB[128 * 16];

    const int t    = threadIdx.x;
    const int lane = t & 63;
    const int wave = t >> 6;
    const int quad = lane >> 4;
    const int l16  = lane & 15;
    const int wm   = wave >> 1;
    const int wn   = wave & 1;

    const int bm0 = blockIdx.y * 128;
    const int bn0 = blockIdx.x * 128;

    const float* gA[4];
    const float* gB[4];
    int ldsIdx[4];
    for (int c = 0; c < 4; c++) {
        const int ch   = t + c * 256;
        const int row  = ch >> 3;
        const int col4 = ch & 7;
        gA[c] = X + (size_t)(bm0 + row) * NDIM + col4 * 4;
        gB[c] = W + (size_t)(bn0 + row) * NDIM + col4 * 4;
        ldsIdx[c] = row * 16 + col4 * 2;
    }

    typedef __bf16 bf16x8_ __attribute__((ext_vector_type(8)));
    const bf16x8* pa = (const bf16x8*)sA + (wm * 64 + l16) * 4 + quad;
    const bf16x8* pb = (const bf16x8*)sB + (wn * 64 + l16) * 4 + quad;

    f32x4 acc[4][4];
    for (int i = 0; i < 4; i++)
        for (int j = 0; j < 4; j++)
            for (int r = 0; r < 4; r++)
                acc[i][j][r] = 0.0f;

    for (int k0 = 0; k0 < NDIM; k0 += 32) {
        float4 va[4], vb[4];
        for (int c = 0; c < 4; c++) {
            va[c] = *(const float4*)(gA[c] + k0);
            vb[c] = *(const float4*)(gB[c] + k0);
        }
        __syncthreads();
        for (int c = 0; c < 4; c++) {
            uint2 ua, ub;
            ua.x = pack_bf2(va[c].x, va[c].y);
            ua.y = pack_bf2(va[c].z, va[c].w);
            ub.x = pack_bf2(vb[c].x, vb[c].y);
            ub.y = pack_bf2(vb[c].z, vb[c].w);
            *(uint2*)(sA + ldsIdx[c]) = ua;
            *(uint2*)(sB + ldsIdx[c]) = ub;
        }
        __syncthreads();

        bf16x8 af[4], bfr[4];
        for (int mt = 0; mt < 4; mt++) af[mt]  = pa[mt * 64];
        for (int nt = 0; nt < 4; nt++) bfr[nt] = pb[nt * 64];

        for (int mt = 0; mt < 4; mt++)
            for (int nt = 0; nt < 4; nt++)
                acc[mt][nt] = __builtin_amdgcn_mfma_f32_16x16x32_bf16(
                    af[mt], bfr[nt], acc[mt][nt], 0, 0, 0);
    }

    const float one_m_beta = 1.0f - Bp[0];
    for (int nt = 0; nt < 4; nt++) {
        const int n = bn0 + wn * 64 + nt * 16 + l16;
        const float br = Br[n];
        for (int mt = 0; mt < 4; mt++) {
            const int mbase = bm0 + wm * 64 + mt * 16 + quad * 4;
            for (int r = 0; r < 4; r++) {
                const size_t idx = (size_t)(mbase + r) * NDIM + n;
                float v = acc[mt][nt][r] + one_m_beta;
                if (v < 0.0f) v = 0.0f;
                float res = 1.0f - br + X[idx] + v;
                if (res < 0.0f) res = 0.0f;
                out[idx] = res;
            }
        }
    }
}

extern "C" void kernel_launch(void* const* d_in, const int* in_sizes, int n_in,
                              void* d_out, int out_size, void* d_ws, size_t ws_size,
                              hipStream_t stream) {
    (void)in_sizes; (void)n_in; (void)out_size;

    const float* X  = (const float*)d_in[0];
    const float* W  = (const float*)d_in[1];
    const float* Bp = (const float*)d_in[2];
    const float* Br = (const float*)d_in[3];
    float* out      = (float*)d_out;

    const size_t elems   = (size_t)NDIM * NDIM;          // 16.7M per matrix
    const size_t bf_need = elems * 2 * 2;                // Xbf + Wbf, 2 B each

    dim3 block(256);

    if (ws_size >= bf_need) {
        unsigned int* Xbf = (unsigned int*)d_ws;
        unsigned int* Wbf = (unsigned int*)d_ws + elems / 2;   // uint = 2 bf16

        dim3 cvt_grid((unsigned int)(elems / 8 / 256));
        hipLaunchKernelGGL(convert_f32_bf16_kernel, cvt_grid, block, 0, stream, X, Xbf);
        hipLaunchKernelGGL(convert_f32_bf16_kernel, cvt_grid, block, 0, stream, W, Wbf);
        hipLaunchKernelGGL(ResFCEventuallyLayer_82205674045459_kernel,
                           dim3(256), dim3(512), 0, stream, Xbf, Wbf, X, Bp, Br, out);
    } else {
        hipLaunchKernelGGL(resfc_fallback_kernel,
                           dim3(NDIM / 128, NDIM / 128), block, 0, stream,
                           X, W, Bp, Br, out);
    }
}